// Round 4
// baseline (270.184 us; speedup 1.0000x reference)
//
#include <hip/hip_runtime.h>

#define BSZ 64
#define QN  1024
#define TN  128
#define NCL 20
#define INFV 1e30f

typedef float f32x2 __attribute__((ext_vector_type(2)));
typedef float f32x4 __attribute__((ext_vector_type(4)));

template<int CTRL>
__device__ __forceinline__ float dpp_min(float x) {
    int r = __builtin_amdgcn_mov_dpp(__float_as_int(x), CTRL, 0xF, 0xF, false);
    return fminf(x, __int_as_float(r));
}
__device__ __forceinline__ float swap32_min(float x) {
    float a = x, b = x;
    asm volatile("v_permlane32_swap_b32 %0, %1" : "+v"(a), "+v"(b));
    return fminf(x, fminf(a, b));
}
__device__ __forceinline__ float swap16_min(float x) {
    float a = x, b = x;
    asm volatile("v_permlane16_swap_b32 %0, %1" : "+v"(a), "+v"(b));
    return fminf(x, fminf(a, b));
}
__device__ __forceinline__ int rdl(int v, int l) {
    return __builtin_amdgcn_readlane(v, l);
}
__device__ __forceinline__ float rdlf(float v, int l) {
    return __int_as_float(__builtin_amdgcn_readlane(__float_as_int(v), l));
}
// select one of 4 per-lane words by uniform index (3 cndmasks)
__device__ __forceinline__ uint32_t sel4(uint32_t a0, uint32_t a1,
                                         uint32_t a2, uint32_t a3, int w) {
    uint32_t r01 = (w & 1) ? a1 : a0;
    uint32_t r23 = (w & 1) ? a3 : a2;
    return (w & 2) ? r23 : r01;
}
// permuted LDS float index: col c = lane*16 + jj*4 + rr -> jj*256 + lane*4 + rr
__device__ __forceinline__ int pidxf(int c) {
    return ((c >> 2) & 3) * 256 + ((c >> 4) << 2) + (c & 3);
}

__global__ __launch_bounds__(64) void lsa_fused_kernel(
    const float* __restrict__ pred_logits, // (B,Q,NC)
    const float* __restrict__ pred_coords, // (B,Q,2)
    const int*   __restrict__ tgt_labels,  // (B,T)
    const float* __restrict__ tgt_joints,  // (B,T,2)
    int*         __restrict__ out)         // pred_idx (B,T) ++ tgt_idx (B,T)
{
    const int b = blockIdx.x;
    const int lane = threadIdx.x;

    __shared__ __align__(16) float probP[NCL * QN]; // 80 KB, permuted layout
    __shared__ __align__(16) float cmS[QN];         // frozen spc (INFV = not in SC)
    __shared__ int c4rS[TN];

    // ---- stage softmax(logits) into LDS (permuted store) ----
    {
        const float* lg = pred_logits + (size_t)b * QN * NCL;
#pragma unroll
        for (int k = 0; k < 16; ++k) {
            int q = k * 64 + lane;
            const f32x4* rp = (const f32x4*)(lg + (size_t)q * NCL); // 80B rows, 16B aligned
            float x[NCL];
            *(f32x4*)&x[0]  = rp[0];
            *(f32x4*)&x[4]  = rp[1];
            *(f32x4*)&x[8]  = rp[2];
            *(f32x4*)&x[12] = rp[3];
            *(f32x4*)&x[16] = rp[4];
            float mx = x[0];
#pragma unroll
            for (int c = 1; c < NCL; ++c) mx = fmaxf(mx, x[c]);
            float e[NCL];
            float ssum = 0.f;
#pragma unroll
            for (int c = 0; c < NCL; ++c) { e[c] = expf(x[c] - mx); ssum += e[c]; }
            int pq = pidxf(q);
#pragma unroll
            for (int c = 0; c < NCL; ++c) probP[c * QN + pq] = e[c] / ssum;
        }
    }

    // ---- per-lane register state (column c = lane*16 + s) ----
    const float2* pc = (const float2*)pred_coords + (size_t)b * QN;
    f32x2 pxp[8], pyp[8], vvp[8];
#pragma unroll
    for (int s = 0; s < 16; ++s) {
        float2 P = pc[lane * 16 + s];
        pxp[s >> 1][s & 1] = P.x;
        pyp[s >> 1][s & 1] = P.y;
        vvp[s >> 1][s & 1] = 0.f;
    }
    // row4col for owned cols: 4 words x 4 bytes, 0xFF = unassigned
    uint32_t rcP0 = 0xFFFFFFFFu, rcP1 = 0xFFFFFFFFu,
             rcP2 = 0xFFFFFFFFu, rcP3 = 0xFFFFFFFFu;

    // rows distributed: lane owns rows lane (A) and lane+64 (B)
    const int*    labs = tgt_labels + (size_t)b * TN;
    const float2* tj   = (const float2*)tgt_joints + (size_t)b * TN;
    int    labA = labs[lane],  labB = labs[lane + 64];
    int    labAB = (labA & 0xFF) | ((labB & 0xFF) << 8);
    float2 tA   = tj[lane],    tB   = tj[lane + 64];
    float  u0 = 0.f, u1 = 0.f;
    int    c4rA = -1, c4rB = -1;        // col4row for owned rows
    __syncthreads();

    const int laneBase = lane * 4;      // float offset within permuted group

    for (int cur = 0; cur < TN; ++cur) {
        float sp[16];
        int   pth[16];
        unsigned scMask = 0;
#pragma unroll
        for (int s = 0; s < 16; ++s) { sp[s] = INFV; pth[s] = 0; }

        float minVal = 0.f;
        int   i_s = cur;
        int   sinkJ = -1;
        int   iters = 0;

        // ---- prologue: broadcast row cur + prefetch its prob row ----
        f32x4 pr4[4];
        float tx, ty, u_i;
        {
            int lw = rdl(labAB, i_s & 63);
            int labI = (lw >> ((i_s >> 6) * 8)) & 0xFF;
            const f32x4* pp = (const f32x4*)&probP[labI * QN + laneBase];
            pr4[0] = pp[0];  pr4[1] = pp[64];
            pr4[2] = pp[128]; pr4[3] = pp[192];
            bool hi = i_s >= 64; int l6 = i_s & 63;
            tx  = rdlf(hi ? tB.x : tA.x, l6);
            ty  = rdlf(hi ? tB.y : tA.y, l6);
            u_i = rdlf(hi ? u1 : u0, l6);
        }

        while (true) {
            // ---- cb precompute (independent of prob; overlaps LDS wait) ----
            f32x2 tx2 = {tx, tx}, ty2 = {ty, ty};
            f32x2 cb[8];
#pragma unroll
            for (int p = 0; p < 8; ++p) {
                f32x2 dx = pxp[p] - tx2;
                f32x2 dy = pyp[p] - ty2;
                cb[p] = __builtin_elementwise_abs(dx) + __builtin_elementwise_abs(dy);
            }

            // ---- relax 16 owned columns (reference float op order) ----
            f32x2 mv2 = {minVal, minVal}, ui2 = {u_i, u_i};
            float mval[16];
#pragma unroll
            for (int p = 0; p < 8; ++p) {
                f32x2 pr;
                pr[0] = pr4[p >> 1][(p & 1) * 2 + 0];
                pr[1] = pr4[p >> 1][(p & 1) * 2 + 1];
                f32x2 cost = cb[p] - pr;                   // bbox + (-prob)
                f32x2 r2 = ((mv2 + cost) - ui2) - vvp[p];
#pragma unroll
                for (int e = 0; e < 2; ++e) {
                    const int s = p * 2 + e;
                    bool unm = ((scMask >> s) & 1u) == 0u;
                    float r = r2[e];
                    bool upd = unm && (r < sp[s]);
                    sp[s]   = upd ? r   : sp[s];
                    pth[s]  = upd ? i_s : pth[s];
                    mval[s] = unm ? sp[s] : INFV;
                }
            }

            // ---- lane-local argmin over 16 slots (first-index tie-break) ----
            float v8[8]; int i8[8];
#pragma unroll
            for (int k = 0; k < 8; ++k) {
                bool t = mval[2 * k + 1] < mval[2 * k];
                v8[k] = t ? mval[2 * k + 1] : mval[2 * k];
                i8[k] = t ? 2 * k + 1 : 2 * k;
            }
            float v4[4]; int i4[4];
#pragma unroll
            for (int k = 0; k < 4; ++k) {
                bool t = v8[2 * k + 1] < v8[2 * k];
                v4[k] = t ? v8[2 * k + 1] : v8[2 * k];
                i4[k] = t ? i8[2 * k + 1] : i8[2 * k];
            }
            float v2[2]; int i2[2];
#pragma unroll
            for (int k = 0; k < 2; ++k) {
                bool t = v4[2 * k + 1] < v4[2 * k];
                v2[k] = t ? v4[2 * k + 1] : v4[2 * k];
                i2[k] = t ? i4[2 * k + 1] : i4[2 * k];
            }
            bool tt = v2[1] < v2[0];
            float lmin = tt ? v2[1] : v2[0];
            int   bi = lane * 16 + (tt ? i2[1] : i2[0]);

            // ---- VALU-only cross-lane min ----
            float g = swap32_min(lmin);
            g = swap16_min(g);
            g = dpp_min<0x128>(g);   // row_ror:8
            g = dpp_min<0x124>(g);   // row_ror:4
            g = dpp_min<0x122>(g);   // row_ror:2
            g = dpp_min<0x121>(g);   // row_ror:1
            float gmin = __int_as_float(
                __builtin_amdgcn_readfirstlane(__float_as_int(g)));

            unsigned long long mk = __ballot(lmin == gmin);
            int L = __ffsll(mk) - 1;
            int j = rdl(bi, L);                 // uniform (SGPR)
            minVal = gmin;

            // ---- SC add + sink test via packed row4col bytes ----
            const int owner = j >> 4, slot = j & 15;
            scMask |= (lane == owner) ? (1u << slot) : 0u;
            uint32_t rcw = sel4(rcP0, rcP1, rcP2, rcP3, slot >> 2);
            int rbyte = (rdl((int)rcw, owner) >> ((slot & 3) * 8)) & 0xFF;
            sinkJ = j;
            if (rbyte == 0xFF) break;           // unassigned col -> sink
            if (++iters > QN + 2) break;        // safety guard

            // ---- prefetch next row's prob + broadcasts (overlap backedge) ----
            i_s = rbyte;
            int lw = rdl(labAB, i_s & 63);
            int labI = (lw >> ((i_s >> 6) * 8)) & 0xFF;
            const f32x4* pp = (const f32x4*)&probP[labI * QN + laneBase];
            pr4[0] = pp[0];  pr4[1] = pp[64];
            pr4[2] = pp[128]; pr4[3] = pp[192];
            bool hi = i_s >= 64; int l6 = i_s & 63;
            tx  = rdlf(hi ? tB.x : tA.x, l6);
            ty  = rdlf(hi ? tB.y : tA.y, l6);
            u_i = rdlf(hi ? u1 : u0, l6);
        }

        // ---- dump frozen spc (sentinel INFV for non-SC), permuted b128 ----
#pragma unroll
        for (int jj = 0; jj < 4; ++jj) {
            f32x4 w;
#pragma unroll
            for (int rr = 0; rr < 4; ++rr) {
                int s = jj * 4 + rr;
                w[rr] = ((scMask >> s) & 1u) ? sp[s] : INFV;
            }
            *(f32x4*)&cmS[jj * 256 + laneBase] = w;
        }
        __syncthreads();

        // ---- dual updates (reference semantics) ----
        if (lane == (cur & 63)) {
            if (cur >= 64) u1 += minVal; else u0 += minVal;
        }
        {
            int c4 = c4rA;
            if (lane != cur && c4 >= 0) {
                float wv = cmS[pidxf(c4)];
                if (wv < 5e29f) u0 += minVal - wv;
            }
        }
        {
            int rr = lane + 64, c4 = c4rB;
            if (rr != cur && c4 >= 0) {
                float wv = cmS[pidxf(c4)];
                if (wv < 5e29f) u1 += minVal - wv;
            }
        }
#pragma unroll
        for (int s = 0; s < 16; ++s) {
            if ((scMask >> s) & 1u)
                vvp[s >> 1][s & 1] -= (minVal - sp[s]);
        }
        __syncthreads();

        // ---- augment along alternating path (packed bytes, uniform walk) ----
        {
            uint32_t p0 = (uint32_t)pth[0]  | ((uint32_t)pth[1]  << 8) |
                          ((uint32_t)pth[2]  << 16) | ((uint32_t)pth[3]  << 24);
            uint32_t p1 = (uint32_t)pth[4]  | ((uint32_t)pth[5]  << 8) |
                          ((uint32_t)pth[6]  << 16) | ((uint32_t)pth[7]  << 24);
            uint32_t p2 = (uint32_t)pth[8]  | ((uint32_t)pth[9]  << 8) |
                          ((uint32_t)pth[10] << 16) | ((uint32_t)pth[11] << 24);
            uint32_t p3 = (uint32_t)pth[12] | ((uint32_t)pth[13] << 8) |
                          ((uint32_t)pth[14] << 16) | ((uint32_t)pth[15] << 24);
            int jx = sinkJ;
            for (int it = 0; it <= TN; ++it) {
                const int slot = jx & 15, owner = jx >> 4;
                const int w = slot >> 2, sh = (slot & 3) * 8;
                uint32_t pw = sel4(p0, p1, p2, p3, w);
                int ii = (rdl((int)pw, owner) >> sh) & 0xFF;
                // row4col[jx] = ii (byte insert on owner lane)
                uint32_t rcw = sel4(rcP0, rcP1, rcP2, rcP3, w);
                uint32_t nw = (rcw & ~(0xFFu << sh)) | ((uint32_t)ii << sh);
                bool me = (lane == owner);
                rcP0 = (me && w == 0) ? nw : rcP0;
                rcP1 = (me && w == 1) ? nw : rcP1;
                rcP2 = (me && w == 2) ? nw : rcP2;
                rcP3 = (me && w == 3) ? nw : rcP3;
                // nj = col4row[ii]; col4row[ii] = jx
                bool hi2 = ii >= 64; int cown = ii & 63;
                int nj = rdl(hi2 ? c4rB : c4rA, cown);
                if (lane == cown) { if (hi2) c4rB = jx; else c4rA = jx; }
                jx = nj;
                if (ii == cur) break;
            }
        }
    }

    // ---- outputs: rank = #smaller (col4row values are distinct) ----
    c4rS[lane] = c4rA;
    c4rS[lane + 64] = c4rB;
    __syncthreads();
#pragma unroll
    for (int h = 0; h < 2; ++h) {
        int t = lane + h * 64;
        int q = h ? c4rB : c4rA;
        int rank = 0;
        for (int s = 0; s < TN; ++s) rank += (c4rS[s] < q) ? 1 : 0;
        out[(size_t)b * TN + rank] = q;            // pred_idx
        out[(size_t)(BSZ + b) * TN + rank] = t;    // tgt_idx
    }
}

extern "C" void kernel_launch(void* const* d_in, const int* in_sizes, int n_in,
                              void* d_out, int out_size, void* d_ws, size_t ws_size,
                              hipStream_t stream) {
    const float* pred_logits = (const float*)d_in[0]; // (B,Q,NC)
    const float* pred_coords = (const float*)d_in[1]; // (B,Q,2)
    const int*   tgt_labels  = (const int*)d_in[2];   // (B,T)
    const float* tgt_joints  = (const float*)d_in[3]; // (B,T,2)

    lsa_fused_kernel<<<BSZ, 64, 0, stream>>>(pred_logits, pred_coords,
                                             tgt_labels, tgt_joints,
                                             (int*)d_out);
}